// Round 1
// 1712.322 us; speedup vs baseline: 1.2016x; 1.2016x over previous
//
#include <hip/hip_runtime.h>
#include <hip/hip_bf16.h>

typedef unsigned short ushort_t;
typedef short short8 __attribute__((ext_vector_type(8)));
typedef float floatx4 __attribute__((ext_vector_type(4)));

#define NB 65536
#define BR 16   // rows per k1 block

// ws layout (bytes):
//   [0, 1015808)        : Wall bf16 — per modality [512][KM], rows 0-127 = Wm,
//                         rows 128-511 = in_w @ Wm   (bases below)
//   [1015808, 1026048)  : ball f32 [5][512] — combined biases (x | qkv)
//   [1026048, 1058816)  : out_w bf16 [128][128]
//   [1058816, 84944896) : Y bf16 [65536][640] (holds x mid-k1, then final y)

__device__ __forceinline__ ushort_t f2bf(float f) {
  __hip_bfloat16 h = __float2bfloat16(f);
  ushort_t u;
  __builtin_memcpy(&u, &h, 2);
  return u;
}
__device__ __forceinline__ float bf2f(ushort_t u) {
  unsigned int x = ((unsigned int)u) << 16;
  return __uint_as_float(x);
}

__constant__ int c_KMs[5] = {128, 256, 64, 32, 512};
__constant__ int c_WB[5] = {0, 65536, 196608, 229376, 245760};  // ushort offsets

// ---------------- K0: weight prep ----------------
__global__ __launch_bounds__(256) void k0_prep(
    const float* __restrict__ Wc, const float* __restrict__ Wm,
    const float* __restrict__ Wd, const float* __restrict__ Wp,
    const float* __restrict__ Wr,
    const float* __restrict__ bc, const float* __restrict__ bm,
    const float* __restrict__ bd, const float* __restrict__ bp,
    const float* __restrict__ br,
    const float* __restrict__ in_w, const float* __restrict__ in_b,
    const float* __restrict__ out_w,
    ushort_t* __restrict__ wall, float* __restrict__ ball,
    ushort_t* __restrict__ outw) {
  const int b = blockIdx.x, t = threadIdx.x;
  const float* Wms[5] = {Wc, Wm, Wd, Wp, Wr};
  const float* bms[5] = {bc, bm, bd, bp, br};
  if (b < 372) {
    // qkv combined weights: Wall_m[128+o3][i] = sum_c in_w[o3][c]*Wm[c][i]
    int idx = b * 256 + t;  // [0, 95232), float4 of i per thread
    int m, loc;
    if (idx < 12288) { m = 0; loc = idx; }
    else if (idx < 36864) { m = 1; loc = idx - 12288; }
    else if (idx < 43008) { m = 2; loc = idx - 36864; }
    else if (idx < 46080) { m = 3; loc = idx - 43008; }
    else { m = 4; loc = idx - 46080; }
    int KM = c_KMs[m], C4 = KM >> 2;
    int o3 = loc / C4, i = (loc - o3 * C4) * 4;
    const float* Wmp = Wms[m];
    float a0 = 0.f, a1 = 0.f, a2 = 0.f, a3 = 0.f;
    for (int c = 0; c < 128; ++c) {
      float w = in_w[o3 * 128 + c];
      float4 v = *(const float4*)(Wmp + c * KM + i);
      a0 += w * v.x; a1 += w * v.y; a2 += w * v.z; a3 += w * v.w;
    }
    ushort_t* dst = wall + c_WB[m] + (128 + o3) * KM + i;
    dst[0] = f2bf(a0); dst[1] = f2bf(a1); dst[2] = f2bf(a2); dst[3] = f2bf(a3);
  } else if (b < 496) {
    // x weights: Wall_m[o][i] = Wm[o][i]
    int idx = (b - 372) * 256 + t;  // [0, 31744)
    int m, loc;
    if (idx < 4096) { m = 0; loc = idx; }
    else if (idx < 12288) { m = 1; loc = idx - 4096; }
    else if (idx < 14336) { m = 2; loc = idx - 12288; }
    else if (idx < 15360) { m = 3; loc = idx - 14336; }
    else { m = 4; loc = idx - 15360; }
    int KM = c_KMs[m], C4 = KM >> 2;
    int o = loc / C4, i = (loc - o * C4) * 4;
    float4 v = *(const float4*)(Wms[m] + o * KM + i);
    ushort_t* dst = wall + c_WB[m] + o * KM + i;
    dst[0] = f2bf(v.x); dst[1] = f2bf(v.y); dst[2] = f2bf(v.z); dst[3] = f2bf(v.w);
  } else if (b < 506) {
    // combined biases
    int idx = (b - 496) * 256 + t;  // [0, 2560)
    if (idx < 2560) {
      int m = idx >> 9, c = idx & 511;
      float v;
      if (c < 128) v = bms[m][c];
      else {
        int o3 = c - 128;
        float a = in_b[o3];
        const float* bmp = bms[m];
        for (int cc = 0; cc < 128; ++cc) a += in_w[o3 * 128 + cc] * bmp[cc];
        v = a;
      }
      ball[idx] = v;
    }
  } else {
    int idx = (b - 506) * 256 + t;  // [0, 4096)
    float4 v = *(const float4*)(out_w + idx * 4);
    ushort_t* dst = outw + idx * 4;
    dst[0] = f2bf(v.x); dst[1] = f2bf(v.y); dst[2] = f2bf(v.z); dst[3] = f2bf(v.w);
  }
}

// ---------------- K1: MFMA fused proj+qkv+MHA+LN -> y bf16 ----------------
// 16 rows/block, 4 waves. Wave w owns output cols [w*128,(w+1)*128) of the
// 512-wide combined (x|q|k|v) GEMM: w0->x (to Y global), w1/2/3->q/k/v (LDS).
// LDS token index tok = m*16 + r; column swizzle c ^= (r&15)<<2 (bank spread).
__global__ __launch_bounds__(256) void k1_fused(
    const float* __restrict__ cat, const float* __restrict__ menu,
    const float* __restrict__ din, const float* __restrict__ pri,
    const float* __restrict__ rev,
    const ushort_t* __restrict__ wall, const float* __restrict__ ball,
    const ushort_t* __restrict__ outw,
    const float* __restrict__ out_b, const float* __restrict__ ln_g,
    const float* __restrict__ ln_b, ushort_t* __restrict__ Y) {
  __shared__ __align__(16) ushort_t s_qkv[80 * 384];  // 61440 B
  const int t = threadIdx.x;
  const int w = t >> 6;
  const int l = t & 63;
  const int lr = l & 15;   // A-row within M-tile
  const int lg = l >> 4;   // k-group (0..3)
  const long r0 = (long)blockIdx.x * BR;

  const float* embp[5] = {cat, menu, din, pri, rev};

  // ---- Phase A: per-modality GEMM [16 x KM] @ [KM x 512] ----
  for (int m = 0; m < 5; ++m) {
    const int KM = c_KMs[m];
    const float* ep = embp[m] + (r0 + lr) * KM + lg * 8;
    const ushort_t* wp = wall + c_WB[m];
    floatx4 acc[8] = {};
    for (int k0 = 0; k0 < KM; k0 += 32) {
      float4 e0 = *(const float4*)(ep + k0);
      float4 e1 = *(const float4*)(ep + k0 + 4);
      short8 af;
      af[0] = (short)f2bf(e0.x); af[1] = (short)f2bf(e0.y);
      af[2] = (short)f2bf(e0.z); af[3] = (short)f2bf(e0.w);
      af[4] = (short)f2bf(e1.x); af[5] = (short)f2bf(e1.y);
      af[6] = (short)f2bf(e1.z); af[7] = (short)f2bf(e1.w);
#pragma unroll
      for (int nt = 0; nt < 8; ++nt) {
        int nrow = w * 128 + nt * 16 + lr;
        short8 bf = *(const short8*)(wp + (long)nrow * KM + k0 + lg * 8);
        acc[nt] =
            __builtin_amdgcn_mfma_f32_16x16x32_bf16(af, bf, acc[nt], 0, 0, 0);
      }
    }
#pragma unroll
    for (int nt = 0; nt < 8; ++nt) {
      int gcol = w * 128 + nt * 16 + lr;
      float bias = ball[m * 512 + gcol];
      if (w == 0) {
#pragma unroll
        for (int i = 0; i < 4; ++i) {
          int row = lg * 4 + i;
          Y[(r0 + row) * 640 + m * 128 + nt * 16 + lr] =
              f2bf(acc[nt][i] + bias);
        }
      } else {
        int qc = gcol - 128;  // 0..383 within (q|k|v)
#pragma unroll
        for (int i = 0; i < 4; ++i) {
          int row = lg * 4 + i;
          s_qkv[(m * 16 + row) * 384 + (qc ^ (row << 2))] =
              f2bf(acc[nt][i] + bias);
        }
      }
    }
  }
  __syncthreads();

  // ---- Phase B: scores + softmax (unit = (m, r, h); 320 units) ----
  float at[2][5];
#pragma unroll
  for (int p = 0; p < 2; ++p) {
    int idx = p * 256 + t;
    if (idx < 320) {
      int m = idx >> 6, rr = (idx >> 2) & 15, h = idx & 3;
      int key = rr << 2;
      const ushort_t* qp = s_qkv + (m * 16 + rr) * 384;
      float qv[32];
#pragma unroll
      for (int d = 0; d < 32; d += 2) {
        unsigned int u = *(const unsigned int*)(qp + ((h * 32 + d) ^ key));
        qv[d] = __uint_as_float(u << 16);
        qv[d + 1] = __uint_as_float(u & 0xffff0000u);
      }
      float sc[5];
#pragma unroll
      for (int n = 0; n < 5; ++n) {
        const ushort_t* kp = s_qkv + (n * 16 + rr) * 384;
        float s = 0.f;
#pragma unroll
        for (int d = 0; d < 32; d += 2) {
          unsigned int u =
              *(const unsigned int*)(kp + ((128 + h * 32 + d) ^ key));
          s += qv[d] * __uint_as_float(u << 16) +
               qv[d + 1] * __uint_as_float(u & 0xffff0000u);
        }
        sc[n] = s * 0.17677669529663689f;
      }
      float mx = fmaxf(fmaxf(fmaxf(sc[0], sc[1]), fmaxf(sc[2], sc[3])), sc[4]);
      float e0 = __expf(sc[0] - mx), e1 = __expf(sc[1] - mx);
      float e2 = __expf(sc[2] - mx), e3 = __expf(sc[3] - mx);
      float e4 = __expf(sc[4] - mx);
      float inv = 1.f / (e0 + e1 + e2 + e3 + e4);
      at[p][0] = e0 * inv; at[p][1] = e1 * inv; at[p][2] = e2 * inv;
      at[p][3] = e3 * inv; at[p][4] = e4 * inv;
    }
  }
  __syncthreads();  // all q/k reads complete before overlaying q with attn
#pragma unroll
  for (int p = 0; p < 2; ++p) {
    int idx = p * 256 + t;
    if (idx < 320) {
      int m = idx >> 6, rr = (idx >> 2) & 15, h = idx & 3;
      int fb = ((rr * 4 + h) * 5 + m) * 5;
#pragma unroll
      for (int n = 0; n < 5; ++n) {
        int f = fb + n;
        *(float*)&s_qkv[(f >> 6) * 384 + ((f & 63) << 1)] = at[p][n];
      }
    }
  }
  __syncthreads();

  // ---- Phase C/D: ctx A-frags + out-proj MFMA + residual + LN ----
  // wave w owns modality M-tile w; wave 0 also does modality 4.
  const int nm = (w == 0) ? 2 : 1;
  for (int mi = 0; mi < nm; ++mi) {
    int m = (mi == 0) ? w : 4;
    floatx4 acc[8] = {};
    const int key = lr << 2;
#pragma unroll
    for (int kk = 0; kk < 4; ++kk) {  // k-step == head
      int fb = ((lr * 4 + kk) * 5 + m) * 5;
      float an[5];
#pragma unroll
      for (int n = 0; n < 5; ++n) {
        int f = fb + n;
        an[n] = *(const float*)&s_qkv[(f >> 6) * 384 + ((f & 63) << 1)];
      }
      short8 ca;
#pragma unroll
      for (int j = 0; j < 8; ++j) {
        int c = kk * 32 + lg * 8 + j;
        float s = 0.f;
#pragma unroll
        for (int n = 0; n < 5; ++n)
          s += an[n] * bf2f(s_qkv[(n * 16 + lr) * 384 + ((256 + c) ^ key)]);
        ca[j] = (short)f2bf(s);
      }
#pragma unroll
      for (int nt = 0; nt < 8; ++nt) {
        short8 bf =
            *(const short8*)(outw + (nt * 16 + lr) * 128 + kk * 32 + lg * 8);
        acc[nt] =
            __builtin_amdgcn_mfma_f32_16x16x32_bf16(ca, bf, acc[nt], 0, 0, 0);
      }
    }
    float ob[8], g8[8], be[8];
#pragma unroll
    for (int nt = 0; nt < 8; ++nt) {
      int col = nt * 16 + lr;
      ob[nt] = out_b[col]; g8[nt] = ln_g[col]; be[nt] = ln_b[col];
    }
#pragma unroll
    for (int i = 0; i < 4; ++i) {
      int row = lg * 4 + i;
      long ybase = (r0 + row) * 640 + m * 128;
      float yv[8];
      float sum = 0.f;
#pragma unroll
      for (int nt = 0; nt < 8; ++nt) {
        float x = bf2f(Y[ybase + nt * 16 + lr]);  // residual (written phase A)
        yv[nt] = acc[nt][i] + ob[nt] + x;
        sum += yv[nt];
      }
#pragma unroll
      for (int d = 1; d < 16; d <<= 1) sum += __shfl_xor(sum, d, 64);
      float mu = sum * (1.0f / 128.0f);
      float vv = 0.f;
#pragma unroll
      for (int nt = 0; nt < 8; ++nt) {
        yv[nt] -= mu;
        vv += yv[nt] * yv[nt];
      }
#pragma unroll
      for (int d = 1; d < 16; d <<= 1) vv += __shfl_xor(vv, d, 64);
      float rs = rsqrtf(vv * (1.0f / 128.0f) + 1e-5f);
#pragma unroll
      for (int nt = 0; nt < 8; ++nt)
        Y[ybase + nt * 16 + lr] = f2bf(yv[nt] * rs * g8[nt] + be[nt]);
    }
  }
}

// ---------------- K2: fusion GEMM, bf16 MFMA, out = y @ fus_w^T + fus_b ----
// A = Y bf16 [65536][640]; B = fus_w f32 [992][640] converted inline while
// staging (rows >= 992 zero-filled).
__global__ __launch_bounds__(256) void k2_gemm(const ushort_t* __restrict__ A,
                                               const float* __restrict__ Bw,
                                               const float* __restrict__ bias,
                                               float* __restrict__ C) {
  constexpr int K = 640, NOUT = 992;
  __shared__ ushort_t As[128 * 32];
  __shared__ ushort_t Bs[128 * 32];
  const int m0 = blockIdx.y * 128;
  const int n0 = blockIdx.x * 128;
  const int t = threadIdx.x;
  const int w = t >> 6, l = t & 63;
  const int wm = (w & 1) * 64, wn = (w >> 1) * 64;
  const int quad = l >> 4, lrr = l & 15;

  floatx4 acc[4][4] = {};

  for (int k0 = 0; k0 < K; k0 += 32) {
    __syncthreads();
#pragma unroll
    for (int i = 0; i < 2; ++i) {
      int flat = i * 256 + t;
      int row = flat >> 2, seg = flat & 3;
      *(int4*)&As[row * 32 + seg * 8] =
          *(const int4*)&A[(long)(m0 + row) * K + k0 + seg * 8];
      int brow = n0 + row;
      short8 bv = {};
      if (brow < NOUT) {
        const float* bp = Bw + (long)brow * K + k0 + seg * 8;
        float4 b0 = *(const float4*)bp;
        float4 b1 = *(const float4*)(bp + 4);
        bv[0] = (short)f2bf(b0.x); bv[1] = (short)f2bf(b0.y);
        bv[2] = (short)f2bf(b0.z); bv[3] = (short)f2bf(b0.w);
        bv[4] = (short)f2bf(b1.x); bv[5] = (short)f2bf(b1.y);
        bv[6] = (short)f2bf(b1.z); bv[7] = (short)f2bf(b1.w);
      }
      *(short8*)&Bs[row * 32 + seg * 8] = bv;
    }
    __syncthreads();
    short8 af[4], bf[4];
#pragma unroll
    for (int mt = 0; mt < 4; ++mt)
      af[mt] = *(const short8*)&As[(wm + mt * 16 + lrr) * 32 + quad * 8];
#pragma unroll
    for (int nt = 0; nt < 4; ++nt)
      bf[nt] = *(const short8*)&Bs[(wn + nt * 16 + lrr) * 32 + quad * 8];
#pragma unroll
    for (int mt = 0; mt < 4; ++mt)
#pragma unroll
      for (int nt = 0; nt < 4; ++nt)
        acc[mt][nt] = __builtin_amdgcn_mfma_f32_16x16x32_bf16(
            af[mt], bf[nt], acc[mt][nt], 0, 0, 0);
  }

#pragma unroll
  for (int mt = 0; mt < 4; ++mt)
#pragma unroll
    for (int nt = 0; nt < 4; ++nt)
#pragma unroll
      for (int i = 0; i < 4; ++i) {
        int row = m0 + wm + mt * 16 + quad * 4 + i;
        int col = n0 + wn + nt * 16 + lrr;
        if (col < NOUT)
          C[(long)row * NOUT + col] = acc[mt][nt][i] + bias[col];
      }
}

// ---------------- launch ----------------
extern "C" void kernel_launch(void* const* d_in, const int* in_sizes, int n_in,
                              void* d_out, int out_size, void* d_ws,
                              size_t ws_size, hipStream_t stream) {
  const float* cat   = (const float*)d_in[0];
  const float* menu  = (const float*)d_in[1];
  const float* din   = (const float*)d_in[2];
  const float* pri   = (const float*)d_in[3];
  const float* rev   = (const float*)d_in[4];
  const float* Wc    = (const float*)d_in[5];
  const float* bc    = (const float*)d_in[6];
  const float* Wm    = (const float*)d_in[7];
  const float* bm    = (const float*)d_in[8];
  const float* Wd    = (const float*)d_in[9];
  const float* bd    = (const float*)d_in[10];
  const float* Wp    = (const float*)d_in[11];
  const float* bp    = (const float*)d_in[12];
  const float* Wr    = (const float*)d_in[13];
  const float* br    = (const float*)d_in[14];
  const float* in_w  = (const float*)d_in[15];
  const float* in_b  = (const float*)d_in[16];
  const float* out_w = (const float*)d_in[17];
  const float* out_b = (const float*)d_in[18];
  const float* ln_g  = (const float*)d_in[19];
  const float* ln_b  = (const float*)d_in[20];
  const float* fus_w = (const float*)d_in[21];
  const float* fus_b = (const float*)d_in[22];

  ushort_t* wall = (ushort_t*)d_ws;
  float* ball    = (float*)((char*)d_ws + 1015808);
  ushort_t* outw = (ushort_t*)((char*)d_ws + 1026048);
  ushort_t* Y    = (ushort_t*)((char*)d_ws + 1058816);
  float* out = (float*)d_out;

  k0_prep<<<522, 256, 0, stream>>>(Wc, Wm, Wd, Wp, Wr, bc, bm, bd, bp, br,
                                   in_w, in_b, out_w, wall, ball, outw);
  k1_fused<<<NB / BR, 256, 0, stream>>>(cat, menu, din, pri, rev, wall, ball,
                                        outw, out_b, ln_g, ln_b, Y);
  dim3 g2(8, NB / 128);
  k2_gemm<<<g2, 256, 0, stream>>>(Y, fus_w, fus_b, out);
}

// Round 3
// 1112.029 us; speedup vs baseline: 1.8502x; 1.5398x over previous
//
#include <hip/hip_runtime.h>
#include <hip/hip_bf16.h>

typedef unsigned short ushort_t;
typedef short short8 __attribute__((ext_vector_type(8)));
typedef float floatx4 __attribute__((ext_vector_type(4)));

#define NB 65536
#define BR 32   // rows per k1 block

// ws layout (bytes):
//   [0, 1015808)          : Wall bf16 — per modality [512][KM]; rows 0-127 = Wm
//                           (x), rows 128-511 = in_w @ Wm (q|k|v)
//   [1015808, 1026048)    : ball f32 [5][512]
//   [1026048, 1058816)    : out_w bf16 [128][128]
//   [1058816, 2369536)    : fus_w bf16 padded [1024][640]
//   [2369536, 86255616)   : Y bf16 [65536][640] (x mid-k1, then final y)

__device__ __forceinline__ ushort_t f2bf(float f) {
  __hip_bfloat16 h = __float2bfloat16(f);
  ushort_t u;
  __builtin_memcpy(&u, &h, 2);
  return u;
}
__device__ __forceinline__ float bf2f(ushort_t u) {
  unsigned int x = ((unsigned int)u) << 16;
  return __uint_as_float(x);
}
__device__ __forceinline__ short8 cvt8(float4 a, float4 b) {
  short8 r;
  r[0] = (short)f2bf(a.x); r[1] = (short)f2bf(a.y);
  r[2] = (short)f2bf(a.z); r[3] = (short)f2bf(a.w);
  r[4] = (short)f2bf(b.x); r[5] = (short)f2bf(b.y);
  r[6] = (short)f2bf(b.z); r[7] = (short)f2bf(b.w);
  return r;
}

#define VMCNT0 asm volatile("s_waitcnt vmcnt(0)" ::: "memory")
#define LGKM0 asm volatile("s_waitcnt lgkmcnt(0)" ::: "memory")
#define SBAR0 __builtin_amdgcn_sched_barrier(0)

// ---------------- K0: weight prep ----------------
__global__ __launch_bounds__(256) void k0_prep(
    const float* __restrict__ Wc, const float* __restrict__ Wm,
    const float* __restrict__ Wd, const float* __restrict__ Wp,
    const float* __restrict__ Wr,
    const float* __restrict__ bc, const float* __restrict__ bm,
    const float* __restrict__ bd, const float* __restrict__ bp,
    const float* __restrict__ br,
    const float* __restrict__ in_w, const float* __restrict__ in_b,
    const float* __restrict__ out_w, const float* __restrict__ fus_w,
    ushort_t* __restrict__ wall, float* __restrict__ ball,
    ushort_t* __restrict__ outw, ushort_t* __restrict__ fwb) {
  const int b = blockIdx.x, t = threadIdx.x;
  const float* Wms[5] = {Wc, Wm, Wd, Wp, Wr};
  const float* bms[5] = {bc, bm, bd, bp, br};
  const int KMs[5] = {128, 256, 64, 32, 512};
  const int WBs[5] = {0, 65536, 196608, 229376, 245760};
  if (b < 372) {
    // qkv combined weights: Wall_m[128+o3][i] = sum_c in_w[o3][c]*Wm[c][i]
    int idx = b * 256 + t;  // [0, 95232), float4 of i per thread
    int m, loc;
    if (idx < 12288) { m = 0; loc = idx; }
    else if (idx < 36864) { m = 1; loc = idx - 12288; }
    else if (idx < 43008) { m = 2; loc = idx - 36864; }
    else if (idx < 46080) { m = 3; loc = idx - 43008; }
    else { m = 4; loc = idx - 46080; }
    int KM = KMs[m], C4 = KM >> 2;
    int o3 = loc / C4, i = (loc - o3 * C4) * 4;
    const float* Wmp = Wms[m];
    float a0 = 0.f, a1 = 0.f, a2 = 0.f, a3 = 0.f;
    for (int c = 0; c < 128; ++c) {
      float w = in_w[o3 * 128 + c];
      float4 v = *(const float4*)(Wmp + c * KM + i);
      a0 += w * v.x; a1 += w * v.y; a2 += w * v.z; a3 += w * v.w;
    }
    ushort_t* dst = wall + WBs[m] + (128 + o3) * KM + i;
    dst[0] = f2bf(a0); dst[1] = f2bf(a1); dst[2] = f2bf(a2); dst[3] = f2bf(a3);
  } else if (b < 496) {
    // x weights
    int idx = (b - 372) * 256 + t;  // [0, 31744)
    int m, loc;
    if (idx < 4096) { m = 0; loc = idx; }
    else if (idx < 12288) { m = 1; loc = idx - 4096; }
    else if (idx < 14336) { m = 2; loc = idx - 12288; }
    else if (idx < 15360) { m = 3; loc = idx - 14336; }
    else { m = 4; loc = idx - 15360; }
    int KM = KMs[m], C4 = KM >> 2;
    int o = loc / C4, i = (loc - o * C4) * 4;
    float4 v = *(const float4*)(Wms[m] + o * KM + i);
    ushort_t* dst = wall + WBs[m] + o * KM + i;
    dst[0] = f2bf(v.x); dst[1] = f2bf(v.y); dst[2] = f2bf(v.z); dst[3] = f2bf(v.w);
  } else if (b < 506) {
    // combined biases
    int idx = (b - 496) * 256 + t;  // [0, 2560)
    if (idx < 2560) {
      int m = idx >> 9, c = idx & 511;
      float v;
      if (c < 128) v = bms[m][c];
      else {
        int o3 = c - 128;
        float a = in_b[o3];
        const float* bmp = bms[m];
        for (int cc = 0; cc < 128; ++cc) a += in_w[o3 * 128 + cc] * bmp[cc];
        v = a;
      }
      ball[idx] = v;
    }
  } else if (b < 522) {
    int idx = (b - 506) * 256 + t;  // [0, 4096)
    float4 v = *(const float4*)(out_w + idx * 4);
    ushort_t* dst = outw + idx * 4;
    dst[0] = f2bf(v.x); dst[1] = f2bf(v.y); dst[2] = f2bf(v.z); dst[3] = f2bf(v.w);
  } else {
    int idx = (b - 522) * 256 + t;  // [0, 655360)
    int n = idx / 640;
    float v = (n < 992) ? fus_w[idx] : 0.0f;
    fwb[idx] = f2bf(v);
  }
}

// ---------------- K1 ----------------
// BR=32 rows/block, 4 waves. Wave w owns cols [w*128,(w+1)*128) of the
// combined (x|q|k|v) 512-wide projection: w0->x (global Y), w1/2/3->q/k/v
// (LDS). Weights staged per-wave into a private 8KB LDS slab via
// global_load_lds (coalesced, barrier-free pipeline: slab freed after the 8
// ds_read_b128 frag reads, next stage overlaps the MFMAs).
__global__ __launch_bounds__(256, 1) void k1_fused(
    const float* __restrict__ cat, const float* __restrict__ menu,
    const float* __restrict__ din, const float* __restrict__ pri,
    const float* __restrict__ rev,
    const ushort_t* __restrict__ wall, const float* __restrict__ ball,
    const ushort_t* __restrict__ outw,
    const float* __restrict__ out_b, const float* __restrict__ ln_g,
    const float* __restrict__ ln_b, ushort_t* __restrict__ Y) {
  __shared__ __align__(16) ushort_t s_qkv[160 * 384];  // 122880 B
  __shared__ __align__(16) ushort_t s_slab[4 * 4096];  // 32768 B

  const int t = threadIdx.x;
  const int w = t >> 6;
  const int l = t & 63;
  const int lr = l & 15;  // A-row within 16-row tile / B-col within tile
  const int lg = l >> 4;  // k-group
  const long r0 = (long)blockIdx.x * BR;
  ushort_t* slabw = s_slab + w * 4096;  // wave-private, 128 rows x 32 shorts

  // ---- Phase A: pipelined projection GEMM, 31 flat k-steps ----
  int m = 0, ks = 0, KM = 128;
  const ushort_t* wp = wall + (w << 7) * 128;  // wall + WB[0] + w*128*KM

  // stage issue helper (macro to keep size arg literal)
#define STAGE(WP, KMv, K0)                                                  \
  {                                                                         \
    int rr_ = l >> 2, ss_ = l & 3;                                          \
    _Pragma("unroll") for (int i_ = 0; i_ < 8; ++i_) {                      \
      const ushort_t* g_ = (WP) + (long)(i_ * 16 + rr_) * (KMv) + (K0) +    \
                           ss_ * 8;                                         \
      __builtin_amdgcn_global_load_lds(                                     \
          (const __attribute__((address_space(1))) void*)g_,                \
          (__attribute__((address_space(3))) void*)(slabw + i_ * 512), 16,  \
          0, 0);                                                            \
    }                                                                       \
  }

  // prologue: embeddings + first slab
  float4 e0a = *(const float4*)(cat + (r0 + lr) * 128 + lg * 8);
  float4 e0b = *(const float4*)(cat + (r0 + lr) * 128 + lg * 8 + 4);
  float4 e1a = *(const float4*)(cat + (r0 + 16 + lr) * 128 + lg * 8);
  float4 e1b = *(const float4*)(cat + (r0 + 16 + lr) * 128 + lg * 8 + 4);
  STAGE(wp, 128, 0);
  VMCNT0;
  SBAR0;
  short8 afc0 = cvt8(e0a, e0b);
  short8 afc1 = cvt8(e1a, e1b);

  floatx4 acc0[8] = {};
  floatx4 acc1[8] = {};

  for (int g = 0; g < 31; ++g) {
    // next-step bookkeeping (wave-uniform scalar)
    const int lastk = (ks == (KM >> 5) - 1);
    const int nm = lastk ? m + 1 : m;
    const int nks = lastk ? 0 : ks + 1;
    const int nKM = (nm == 0)   ? 128
                    : (nm == 1) ? 256
                    : (nm == 2) ? 64
                    : (nm == 3) ? 32
                                : 512;
    const int nWB = (nm == 0)   ? 0
                    : (nm == 1) ? 65536
                    : (nm == 2) ? 196608
                    : (nm == 3) ? 229376
                                : 245760;
    const float* nep = (nm == 0)   ? cat
                       : (nm == 1) ? menu
                       : (nm == 2) ? din
                       : (nm == 3) ? pri
                                   : rev;
    const ushort_t* nwp = wall + nWB + (w << 7) * nKM;
    const int nk0 = nks * 32;

    if (g < 30) {  // issue next-step embeddings as early as possible
      e0a = *(const float4*)(nep + (r0 + lr) * nKM + nk0 + lg * 8);
      e0b = *(const float4*)(nep + (r0 + lr) * nKM + nk0 + lg * 8 + 4);
      e1a = *(const float4*)(nep + (r0 + 16 + lr) * nKM + nk0 + lg * 8);
      e1b = *(const float4*)(nep + (r0 + 16 + lr) * nKM + nk0 + lg * 8 + 4);
    }

    // frag reads from current slab
    short8 bf[8];
#pragma unroll
    for (int nt = 0; nt < 8; ++nt)
      bf[nt] = *(const short8*)&s_slab[w * 4096 + (nt * 16 + lr) * 32 + lg * 8];

    LGKM0;  // frag reads done -> slab free for restage
    SBAR0;
    if (g < 30) STAGE(nwp, nKM, nk0);

#pragma unroll
    for (int nt = 0; nt < 8; ++nt) {
      acc0[nt] =
          __builtin_amdgcn_mfma_f32_16x16x32_bf16(afc0, bf[nt], acc0[nt], 0, 0, 0);
      acc1[nt] =
          __builtin_amdgcn_mfma_f32_16x16x32_bf16(afc1, bf[nt], acc1[nt], 0, 0, 0);
    }

    if (lastk) {
      // epilogue for modality m (overlaps stage flight)
#pragma unroll
      for (int nt = 0; nt < 8; ++nt) {
        int gcol = w * 128 + nt * 16 + lr;
        float bias = ball[m * 512 + gcol];
        if (w == 0) {
#pragma unroll
          for (int i = 0; i < 4; ++i) {
            int rb = lg * 4 + i;
            Y[(r0 + rb) * 640 + m * 128 + nt * 16 + lr] =
                f2bf(acc0[nt][i] + bias);
            Y[(r0 + 16 + rb) * 640 + m * 128 + nt * 16 + lr] =
                f2bf(acc1[nt][i] + bias);
          }
        } else {
          int qc = gcol - 128;
#pragma unroll
          for (int i = 0; i < 4; ++i) {
            int rb = lg * 4 + i;
            s_qkv[(m * 32 + rb) * 384 + (qc ^ (rb << 2))] =
                f2bf(acc0[nt][i] + bias);
            s_qkv[(m * 32 + 16 + rb) * 384 + (qc ^ (rb << 2))] =
                f2bf(acc1[nt][i] + bias);
          }
        }
        acc0[nt] = (floatx4){0.f, 0.f, 0.f, 0.f};
        acc1[nt] = (floatx4){0.f, 0.f, 0.f, 0.f};
      }
    }

    if (g < 30) {
      afc0 = cvt8(e0a, e0b);  // compiler waits the emb loads here
      afc1 = cvt8(e1a, e1b);
      VMCNT0;  // next slab landed
      SBAR0;
    }
    m = nm; ks = nks; KM = nKM;
  }
  __syncthreads();

  // ---- Phase B: scores + softmax; unit = (m, rr, h), 640 units ----
  float at[3][5];
#pragma unroll
  for (int p = 0; p < 3; ++p) {
    int idx = p * 256 + t;
    if (idx < 640) {
      int mm = idx >> 7, rr = (idx >> 2) & 31, h = idx & 3;
      int key = (rr & 15) << 2;
      const ushort_t* qp = s_qkv + (mm * 32 + rr) * 384;
      float qv[32];
#pragma unroll
      for (int d = 0; d < 32; d += 2) {
        unsigned int u = *(const unsigned int*)(qp + ((h * 32 + d) ^ key));
        qv[d] = __uint_as_float(u << 16);
        qv[d + 1] = __uint_as_float(u & 0xffff0000u);
      }
      float sc[5];
#pragma unroll
      for (int n = 0; n < 5; ++n) {
        const ushort_t* kp = s_qkv + (n * 32 + rr) * 384;
        float s = 0.f;
#pragma unroll
        for (int d = 0; d < 32; d += 2) {
          unsigned int u =
              *(const unsigned int*)(kp + ((128 + h * 32 + d) ^ key));
          s += qv[d] * __uint_as_float(u << 16) +
               qv[d + 1] * __uint_as_float(u & 0xffff0000u);
        }
        sc[n] = s * 0.17677669529663689f;
      }
      float mx = fmaxf(fmaxf(fmaxf(sc[0], sc[1]), fmaxf(sc[2], sc[3])), sc[4]);
      float e0 = __expf(sc[0] - mx), e1 = __expf(sc[1] - mx);
      float e2 = __expf(sc[2] - mx), e3 = __expf(sc[3] - mx);
      float e4 = __expf(sc[4] - mx);
      float inv = 1.f / (e0 + e1 + e2 + e3 + e4);
      at[p][0] = e0 * inv; at[p][1] = e1 * inv; at[p][2] = e2 * inv;
      at[p][3] = e3 * inv; at[p][4] = e4 * inv;
    }
  }
  __syncthreads();  // q/k reads done before attn overlays q region
#pragma unroll
  for (int p = 0; p < 3; ++p) {
    int idx = p * 256 + t;
    if (idx < 640) {
      int mm = idx >> 7, rr = (idx >> 2) & 31, h = idx & 3;
      int fb = ((rr * 4 + h) * 5 + mm) * 5;
#pragma unroll
      for (int n = 0; n < 5; ++n) {
        int f = fb + n;  // f < 3200 -> rows 0..49 of q region
        *(float*)&s_qkv[(f >> 6) * 384 + ((f & 63) << 1)] = at[p][n];
      }
    }
  }
  __syncthreads();

  // ---- Phase C/D: ctx + out-proj MFMA + residual + LN ----
  // 10 units (m, rt); wave w handles {w, w+4, w+8}
  for (int u = w; u < 10; u += 4) {
    int mm = u >> 1, rt = u & 1;
    int rr = rt * 16 + lr;
    const int key = lr << 2;
    floatx4 acc[8] = {};
#pragma unroll
    for (int kk = 0; kk < 4; ++kk) {  // k-step == head
      int fb = ((rr * 4 + kk) * 5 + mm) * 5;
      float an[5];
#pragma unroll
      for (int n = 0; n < 5; ++n) {
        int f = fb + n;
        an[n] = *(const float*)&s_qkv[(f >> 6) * 384 + ((f & 63) << 1)];
      }
      short8 ca;
#pragma unroll
      for (int j = 0; j < 8; ++j) {
        int c = kk * 32 + lg * 8 + j;
        float s = 0.f;
#pragma unroll
        for (int n = 0; n < 5; ++n)
          s += an[n] * bf2f(s_qkv[(n * 32 + rr) * 384 + ((256 + c) ^ key)]);
        ca[j] = (short)f2bf(s);
      }
#pragma unroll
      for (int nt = 0; nt < 8; ++nt) {
        short8 bfr =
            *(const short8*)&outw[(nt * 16 + lr) * 128 + kk * 32 + lg * 8];
        acc[nt] =
            __builtin_amdgcn_mfma_f32_16x16x32_bf16(ca, bfr, acc[nt], 0, 0, 0);
      }
    }
    float ob[8], g8[8], be[8];
#pragma unroll
    for (int nt = 0; nt < 8; ++nt) {
      int col = nt * 16 + lr;
      ob[nt] = out_b[col]; g8[nt] = ln_g[col]; be[nt] = ln_b[col];
    }
#pragma unroll
    for (int i = 0; i < 4; ++i) {
      int rb = rt * 16 + lg * 4 + i;
      long ybase = (r0 + rb) * 640 + mm * 128;
      float yv[8];
      float sum = 0.f;
#pragma unroll
      for (int nt = 0; nt < 8; ++nt) {
        float x = bf2f(Y[ybase + nt * 16 + lr]);  // residual from phase A
        yv[nt] = acc[nt][i] + ob[nt] + x;
        sum += yv[nt];
      }
#pragma unroll
      for (int d = 1; d < 16; d <<= 1) sum += __shfl_xor(sum, d, 64);
      float mu = sum * (1.0f / 128.0f);
      float vv = 0.f;
#pragma unroll
      for (int nt = 0; nt < 8; ++nt) {
        yv[nt] -= mu;
        vv += yv[nt] * yv[nt];
      }
#pragma unroll
      for (int d = 1; d < 16; d <<= 1) vv += __shfl_xor(vv, d, 64);
      float rs = rsqrtf(vv * (1.0f / 128.0f) + 1e-5f);
#pragma unroll
      for (int nt = 0; nt < 8; ++nt)
        Y[ybase + nt * 16 + lr] = f2bf(yv[nt] * rs * g8[nt] + be[nt]);
    }
  }
#undef STAGE
}

// ---------------- K2: fusion GEMM, bf16 MFMA, out = y @ fus_w^T + fus_b ----
__global__ __launch_bounds__(256) void k2_gemm(const ushort_t* __restrict__ A,
                                               const ushort_t* __restrict__ Bt,
                                               const float* __restrict__ bias,
                                               float* __restrict__ C) {
  constexpr int K = 640, NOUT = 992;
  __shared__ ushort_t As[128 * 32];
  __shared__ ushort_t Bs[128 * 32];
  const int m0 = blockIdx.y * 128;
  const int n0 = blockIdx.x * 128;
  const int t = threadIdx.x;
  const int w = t >> 6, l = t & 63;
  const int wm = (w & 1) * 64, wn = (w >> 1) * 64;
  const int quad = l >> 4, lrr = l & 15;

  floatx4 acc[4][4] = {};

  for (int k0 = 0; k0 < K; k0 += 32) {
    __syncthreads();
#pragma unroll
    for (int i = 0; i < 2; ++i) {
      int flat = i * 256 + t;
      int row = flat >> 2, seg = flat & 3;
      *(int4*)&As[row * 32 + seg * 8] =
          *(const int4*)&A[(long)(m0 + row) * K + k0 + seg * 8];
      *(int4*)&Bs[row * 32 + seg * 8] =
          *(const int4*)&Bt[(long)(n0 + row) * K + k0 + seg * 8];
    }
    __syncthreads();
    short8 af[4], bf[4];
#pragma unroll
    for (int mt = 0; mt < 4; ++mt)
      af[mt] = *(const short8*)&As[(wm + mt * 16 + lrr) * 32 + quad * 8];
#pragma unroll
    for (int nt = 0; nt < 4; ++nt)
      bf[nt] = *(const short8*)&Bs[(wn + nt * 16 + lrr) * 32 + quad * 8];
#pragma unroll
    for (int mt = 0; mt < 4; ++mt)
#pragma unroll
      for (int nt = 0; nt < 4; ++nt)
        acc[mt][nt] = __builtin_amdgcn_mfma_f32_16x16x32_bf16(
            af[mt], bf[nt], acc[mt][nt], 0, 0, 0);
  }

#pragma unroll
  for (int mt = 0; mt < 4; ++mt)
#pragma unroll
    for (int nt = 0; nt < 4; ++nt)
#pragma unroll
      for (int i = 0; i < 4; ++i) {
        int row = m0 + wm + mt * 16 + quad * 4 + i;
        int col = n0 + wn + nt * 16 + lrr;
        if (col < NOUT)
          C[(long)row * NOUT + col] = acc[mt][nt][i] + bias[col];
      }
}

// ---------------- launch ----------------
extern "C" void kernel_launch(void* const* d_in, const int* in_sizes, int n_in,
                              void* d_out, int out_size, void* d_ws,
                              size_t ws_size, hipStream_t stream) {
  const float* cat   = (const float*)d_in[0];
  const float* menu  = (const float*)d_in[1];
  const float* din   = (const float*)d_in[2];
  const float* pri   = (const float*)d_in[3];
  const float* rev   = (const float*)d_in[4];
  const float* Wc    = (const float*)d_in[5];
  const float* bc    = (const float*)d_in[6];
  const float* Wm    = (const float*)d_in[7];
  const float* bm    = (const float*)d_in[8];
  const float* Wd    = (const float*)d_in[9];
  const float* bd    = (const float*)d_in[10];
  const float* Wp    = (const float*)d_in[11];
  const float* bp    = (const float*)d_in[12];
  const float* Wr    = (const float*)d_in[13];
  const float* br    = (const float*)d_in[14];
  const float* in_w  = (const float*)d_in[15];
  const float* in_b  = (const float*)d_in[16];
  const float* out_w = (const float*)d_in[17];
  const float* out_b = (const float*)d_in[18];
  const float* ln_g  = (const float*)d_in[19];
  const float* ln_b  = (const float*)d_in[20];
  const float* fus_w = (const float*)d_in[21];
  const float* fus_b = (const float*)d_in[22];

  ushort_t* wall = (ushort_t*)d_ws;
  float* ball    = (float*)((char*)d_ws + 1015808);
  ushort_t* outw = (ushort_t*)((char*)d_ws + 1026048);
  ushort_t* fwb  = (ushort_t*)((char*)d_ws + 1058816);
  ushort_t* Y    = (ushort_t*)((char*)d_ws + 2369536);
  float* out = (float*)d_out;

  k0_prep<<<3082, 256, 0, stream>>>(Wc, Wm, Wd, Wp, Wr, bc, bm, bd, bp, br,
                                    in_w, in_b, out_w, fus_w, wall, ball, outw,
                                    fwb);
  k1_fused<<<NB / BR, 256, 0, stream>>>(cat, menu, din, pri, rev, wall, ball,
                                        outw, out_b, ln_g, ln_b, Y);
  dim3 g2(8, NB / 128);
  k2_gemm<<<g2, 256, 0, stream>>>(Y, fwb, fus_b, out);
}